// Round 8
// baseline (211.016 us; speedup 1.0000x reference)
//
#include <hip/hip_runtime.h>
#include <stdint.h>

typedef __bf16 bf16;
typedef __attribute__((ext_vector_type(2))) __bf16 bf16x2;
typedef __attribute__((ext_vector_type(4))) __bf16 bf16x4;
typedef __attribute__((ext_vector_type(8))) __bf16 bf16x8;
typedef __attribute__((ext_vector_type(4))) float f32x4;

#define B_  2
#define S_  2048
#define H_  1024
#define NH_ 16
#define HD_ 64
#define ST  72    // Qs/Ks hd-stride (64 + 8 pad)
#define STV 136   // Vt/Ps key-stride (128 + 8 pad)

// async 16B global->LDS. LDS dest = wave-uniform base + lane*16.
// Proper addrspacecast (NOT uintptr truncation).
__device__ __forceinline__ void glds16(const bf16* g, bf16* l) {
  __builtin_amdgcn_global_load_lds(
      (const __attribute__((address_space(1))) uint32_t*)g,
      (__attribute__((address_space(3))) uint32_t*)l, 16, 0, 0);
}

// ---------------------------------------------------------------------------
// fp32 -> bf16 conversion: y=0 hidden_states, y=1..4 weight matrices.
// ---------------------------------------------------------------------------
__global__ __launch_bounds__(256) void cvt_f32_bf16(
    const float* __restrict__ s0, bf16* __restrict__ d0, int n0,
    const float* __restrict__ s1, bf16* __restrict__ d1,
    const float* __restrict__ s2, bf16* __restrict__ d2,
    const float* __restrict__ s3, bf16* __restrict__ d3,
    const float* __restrict__ s4, bf16* __restrict__ d4, int nw)
{
  const float* s; bf16* d; int n;
  switch (blockIdx.y) {
    case 0:  s = s0; d = d0; n = n0; break;
    case 1:  s = s1; d = d1; n = nw; break;
    case 2:  s = s2; d = d2; n = nw; break;
    case 3:  s = s3; d = d3; n = nw; break;
    default: s = s4; d = d4; n = nw; break;
  }
  const int i = (blockIdx.x * 256 + threadIdx.x) * 8;
  if (i >= n) return;
  float4 v0 = *(const float4*)(s + i);
  float4 v1 = *(const float4*)(s + i + 4);
  bf16x8 o;
  o[0] = (bf16)v0.x; o[1] = (bf16)v0.y; o[2] = (bf16)v0.z; o[3] = (bf16)v0.w;
  o[4] = (bf16)v1.x; o[5] = (bf16)v1.y; o[6] = (bf16)v1.z; o[7] = (bf16)v1.w;
  *(bf16x8*)(d + i) = o;
}

// ---------------------------------------------------------------------------
// GEMM: Y[m,n] = sum_k X[m,k]*W[n,k] + bias[n], all-bf16, fp32 bias.
// 128x128 tile, BK=32, m97 structure: global_load_lds width-16 staging.
// ---------------------------------------------------------------------------
template <typename TY>
__global__ __launch_bounds__(256) void gemm_bt_bias(
    const bf16* __restrict__ X,
    const bf16* __restrict__ W0, const bf16* __restrict__ W1, const bf16* __restrict__ W2,
    const float* __restrict__ b0, const float* __restrict__ b1, const float* __restrict__ b2,
    TY* __restrict__ Y0, TY* __restrict__ Y1, TY* __restrict__ Y2,
    int M, int N, int K)
{
  const bf16* W; const float* bias; TY* Y;
  if (blockIdx.z == 0)      { W = W0; bias = b0; Y = Y0; }
  else if (blockIdx.z == 1) { W = W1; bias = b1; Y = Y1; }
  else                      { W = W2; bias = b2; Y = Y2; }

  __shared__ __align__(16) bf16 As[128 * 32];
  __shared__ __align__(16) bf16 Bs[128 * 32];

  const int tid  = threadIdx.x;
  const int lane = tid & 63;
  const int wave = tid >> 6;
  const int m0 = blockIdx.y * 128;
  const int n0 = blockIdx.x * 128;
  const int wm = (wave >> 1) * 64;
  const int wn = (wave & 1) * 64;

  f32x4 acc[4][4] = {};

  for (int k0 = 0; k0 < K; k0 += 32) {
    __syncthreads();   // previous compute done before overwriting LDS
#pragma unroll
    for (int it = 0; it < 2; ++it) {
      const int c   = it * 256 + tid;        // chunk id 0..511 (16B chunks)
      const int row = c >> 2;
      const int col = (c & 3) * 8;
      const int cb  = (it * 256 + wave * 64) * 8;   // wave-uniform elem base
      glds16(X + (size_t)(m0 + row) * K + k0 + col, As + cb);
      glds16(W + (size_t)(n0 + row) * K + k0 + col, Bs + cb);
    }
    __syncthreads();   // drains vmcnt -> tiles resident

    bf16x8 a[4], b[4];
#pragma unroll
    for (int i = 0; i < 4; ++i)
      a[i] = *(const bf16x8*)&As[(wm + i * 16 + (lane & 15)) * 32 + (lane >> 4) * 8];
#pragma unroll
    for (int i = 0; i < 4; ++i)
      b[i] = *(const bf16x8*)&Bs[(wn + i * 16 + (lane & 15)) * 32 + (lane >> 4) * 8];
#pragma unroll
    for (int mi = 0; mi < 4; ++mi)
#pragma unroll
      for (int ni = 0; ni < 4; ++ni)
        acc[mi][ni] = __builtin_amdgcn_mfma_f32_16x16x32_bf16(a[mi], b[ni], acc[mi][ni], 0, 0, 0);
  }

#pragma unroll
  for (int mi = 0; mi < 4; ++mi) {
    const int row = m0 + wm + mi * 16 + (lane >> 4) * 4;
#pragma unroll
    for (int ni = 0; ni < 4; ++ni) {
      const int col = n0 + wn + ni * 16 + (lane & 15);
      const float bv = bias[col];
#pragma unroll
      for (int r = 0; r < 4; ++r)
        Y[(size_t)(row + r) * N + col] = (TY)(acc[mi][ni][r] + bv);
    }
  }
}

// ---------------------------------------------------------------------------
// Flash attention, causal, transposed-score orientation, exp2-domain softmax.
// Block: 256 thr (4 waves), TWO 64-row q-tiles (qt, 31-qt) -> 17 iters/block.
// Wave owns 16 q-rows; lane's row = l15. Mask applied only on last k-iter.
// ---------------------------------------------------------------------------
__global__ __launch_bounds__(256) void attn_causal(
    const bf16* __restrict__ Q, const bf16* __restrict__ K,
    const bf16* __restrict__ V, bf16* __restrict__ O)
{
  const int pair = blockIdx.x;         // 0..15
  const int bh   = blockIdx.y;         // 0..31
  const int b    = bh >> 4;
  const int h    = bh & 15;

  const int tid  = threadIdx.x;
  const int lane = tid & 63;
  const int wave = tid >> 6;
  const int quad = lane >> 4;
  const int l15  = lane & 15;
  const size_t headoff = (size_t)b * S_ * H_ + (size_t)h * HD_;
  const float SCL = 0.125f * 1.44269504f;   // (1/sqrt(64)) * log2(e)

  __shared__ __align__(16) bf16 Qs[64 * ST];
  __shared__ __align__(16) bf16 Ks[128 * ST];
  __shared__ __align__(16) bf16 Vt[64 * STV];       // Vt[d][key]
  __shared__ __align__(16) bf16 Ps[4][16 * STV];    // P[qrow][key] per wave

  for (int phase = 0; phase < 2; ++phase) {
    const int qt = phase ? (31 - pair) : pair;
    const int q0 = qt * 64;
    __syncthreads();   // prior phase done reading Qs

#pragma unroll
    for (int it = 0; it < 2; ++it) {
      const int c = it * 256 + tid, row = c >> 3, col = (c & 7) * 8;
      *(bf16x8*)&Qs[row * ST + col] =
          *(const bf16x8*)(Q + headoff + (size_t)(q0 + row) * H_ + col);
    }

    const int qrow = q0 + wave * 16 + l15;
    float mr = -1e30f, lr = 0.0f;
    f32x4 oacc[4] = {};

    const int niter = (qt >> 1) + 1;
    for (int it = 0; it < niter; ++it) {
      const int k0 = it * 128;
      __syncthreads();

      // stage K tile 128x64
#pragma unroll
      for (int j = 0; j < 4; ++j) {
        const int c = j * 256 + tid, row = c >> 3, col = (c & 7) * 8;
        *(bf16x8*)&Ks[row * ST + col] =
            *(const bf16x8*)(K + headoff + (size_t)(k0 + row) * H_ + col);
      }
      // stage V transposed
      {
        const int vr = (tid & 63) * 2;
        const int vc = (tid >> 6) * 16;
        bf16x8 a0 = *(const bf16x8*)(V + headoff + (size_t)(k0 + vr) * H_ + vc);
        bf16x8 a1 = *(const bf16x8*)(V + headoff + (size_t)(k0 + vr) * H_ + vc + 8);
        bf16x8 c0 = *(const bf16x8*)(V + headoff + (size_t)(k0 + vr + 1) * H_ + vc);
        bf16x8 c1 = *(const bf16x8*)(V + headoff + (size_t)(k0 + vr + 1) * H_ + vc + 8);
#pragma unroll
        for (int e = 0; e < 8; ++e) {
          bf16x2 p0; p0[0] = a0[e]; p0[1] = c0[e];
          *(bf16x2*)&Vt[(vc + e) * STV + vr] = p0;
          bf16x2 p1; p1[0] = a1[e]; p1[1] = c1[e];
          *(bf16x2*)&Vt[(vc + 8 + e) * STV + vr] = p1;
        }
      }
      __syncthreads();

      // ---- S^T = K Q^T ----
      f32x4 sacc[8] = {};
#pragma unroll
      for (int ks = 0; ks < 2; ++ks) {
        bf16x8 bq = *(const bf16x8*)&Qs[(wave * 16 + l15) * ST + ks * 32 + quad * 8];
#pragma unroll
        for (int mb = 0; mb < 8; ++mb) {
          bf16x8 ak = *(const bf16x8*)&Ks[(mb * 16 + l15) * ST + ks * 32 + quad * 8];
          sacc[mb] = __builtin_amdgcn_mfma_f32_16x16x32_bf16(ak, bq, sacc[mb], 0, 0, 0);
        }
      }

      // scale (log2 domain); mask only on the final k-tile
      float sv[8][4];
      if (it == niter - 1) {
#pragma unroll
        for (int mb = 0; mb < 8; ++mb) {
          const int kb = k0 + mb * 16 + quad * 4;
#pragma unroll
          for (int r = 0; r < 4; ++r) {
            const float s = sacc[mb][r] * SCL;
            sv[mb][r] = (kb + r > qrow) ? -1e30f : s;
          }
        }
      } else {
#pragma unroll
        for (int mb = 0; mb < 8; ++mb)
#pragma unroll
          for (int r = 0; r < 4; ++r)
            sv[mb][r] = sacc[mb][r] * SCL;
      }

      // row max: in-lane tree + 2 shuffles
      float mx = -1e30f;
#pragma unroll
      for (int mb = 0; mb < 8; ++mb)
        mx = fmaxf(mx, fmaxf(fmaxf(sv[mb][0], sv[mb][1]), fmaxf(sv[mb][2], sv[mb][3])));
      mx = fmaxf(mx, __shfl_xor(mx, 16, 64));
      mx = fmaxf(mx, __shfl_xor(mx, 32, 64));
      const float mnew  = fmaxf(mr, mx);
      const float alpha = __builtin_amdgcn_exp2f(mr - mnew);
      mr = mnew;

      // exp2, P write (b64 contiguous), sum
      float sum = 0.0f;
#pragma unroll
      for (int mb = 0; mb < 8; ++mb) {
        bf16x4 pw;
#pragma unroll
        for (int r = 0; r < 4; ++r) {
          const float p = __builtin_amdgcn_exp2f(sv[mb][r] - mnew);
          sum += p;
          pw[r] = (bf16)p;
        }
        *(bf16x4*)&Ps[wave][l15 * STV + mb * 16 + quad * 4] = pw;
      }
      sum += __shfl_xor(sum, 16, 64);
      sum += __shfl_xor(sum, 32, 64);
      lr = lr * alpha + sum;
#pragma unroll
      for (int mb = 0; mb < 4; ++mb)
#pragma unroll
        for (int r = 0; r < 4; ++r) oacc[mb][r] *= alpha;

      // ---- O^T += V^T P^T ----
#pragma unroll
      for (int ks = 0; ks < 4; ++ks) {
        bf16x8 bp = *(const bf16x8*)&Ps[wave][l15 * STV + ks * 32 + quad * 8];
#pragma unroll
        for (int mb = 0; mb < 4; ++mb) {
          bf16x8 av = *(const bf16x8*)&Vt[(mb * 16 + l15) * STV + ks * 32 + quad * 8];
          oacc[mb] = __builtin_amdgcn_mfma_f32_16x16x32_bf16(av, bp, oacc[mb], 0, 0, 0);
        }
      }
    }

    // epilogue
    const float inv = 1.0f / lr;
#pragma unroll
    for (int mb = 0; mb < 4; ++mb) {
      bf16x4 o;
#pragma unroll
      for (int r = 0; r < 4; ++r) o[r] = (bf16)(oacc[mb][r] * inv);
      *(bf16x4*)(O + headoff + (size_t)qrow * H_ + mb * 16 + quad * 4) = o;
    }
  }
}

extern "C" void kernel_launch(void* const* d_in, const int* in_sizes, int n_in,
                              void* d_out, int out_size, void* d_ws, size_t ws_size,
                              hipStream_t stream) {
  const float* hs = (const float*)d_in[0];
  const float* Wq = (const float*)d_in[1]; const float* bq = (const float*)d_in[2];
  const float* Wk = (const float*)d_in[3]; const float* bk = (const float*)d_in[4];
  const float* Wv = (const float*)d_in[5]; const float* bv = (const float*)d_in[6];
  const float* Wo = (const float*)d_in[7]; const float* bo = (const float*)d_in[8];
  float* out = (float*)d_out;

  const size_t elems = (size_t)B_ * S_ * H_;   // 4,194,304
  const size_t wel   = (size_t)H_ * H_;        // 1,048,576
  // workspace (40 MB): [hsb | AO aliased 8MB][W bf16 8MB][Q 8][K 8][V 8]
  bf16* hsb = (bf16*)d_ws;      // read only by QKV GEMM
  bf16* AO  = hsb;              // written by attn (hsb dead by then)
  bf16* Wqb = hsb + elems;
  bf16* Wkb = Wqb + wel;
  bf16* Wvb = Wkb + wel;
  bf16* Wob = Wvb + wel;
  bf16* Qw  = Wob + wel;
  bf16* Kw  = Qw + elems;
  bf16* Vw  = Kw + elems;

  cvt_f32_bf16<<<dim3(2048, 5), dim3(256), 0, stream>>>(
      hs, hsb, (int)elems, Wq, Wqb, Wk, Wkb, Wv, Wvb, Wo, Wob, (int)wel);

  const int M = B_ * S_;   // 4096
  gemm_bt_bias<bf16><<<dim3(H_ / 128, M / 128, 3), dim3(256), 0, stream>>>(
      hsb, Wqb, Wkb, Wvb, bq, bk, bv, Qw, Kw, Vw, M, H_, H_);

  attn_causal<<<dim3(16, B_ * NH_), dim3(256), 0, stream>>>(Qw, Kw, Vw, AO);

  gemm_bt_bias<float><<<dim3(H_ / 128, M / 128, 1), dim3(256), 0, stream>>>(
      AO, Wob, Wob, Wob, bo, bo, bo, out, out, out, M, H_, H_);
}

// Round 9
// 203.674 us; speedup vs baseline: 1.0360x; 1.0360x over previous
//
#include <hip/hip_runtime.h>
#include <stdint.h>

typedef __bf16 bf16;
typedef __attribute__((ext_vector_type(2))) __bf16 bf16x2;
typedef __attribute__((ext_vector_type(4))) __bf16 bf16x4;
typedef __attribute__((ext_vector_type(8))) __bf16 bf16x8;
typedef __attribute__((ext_vector_type(4))) float f32x4;

#define B_  2
#define S_  2048
#define H_  1024
#define NH_ 16
#define HD_ 64
#define ST  72    // Qs/Ks hd-stride (64 + 8 pad)
#define STV 136   // Vt/Ps key-stride (128 + 8 pad)

// async 16B global->LDS. LDS dest = wave-uniform base + lane*16.
__device__ __forceinline__ void glds16(const bf16* g, bf16* l) {
  __builtin_amdgcn_global_load_lds(
      (const __attribute__((address_space(1))) uint32_t*)g,
      (__attribute__((address_space(3))) uint32_t*)l, 16, 0, 0);
}

// ---------------------------------------------------------------------------
// fp32 -> bf16 conversion: y=0 hidden_states, y=1..4 weight matrices.
// ---------------------------------------------------------------------------
__global__ __launch_bounds__(256) void cvt_f32_bf16(
    const float* __restrict__ s0, bf16* __restrict__ d0, int n0,
    const float* __restrict__ s1, bf16* __restrict__ d1,
    const float* __restrict__ s2, bf16* __restrict__ d2,
    const float* __restrict__ s3, bf16* __restrict__ d3,
    const float* __restrict__ s4, bf16* __restrict__ d4, int nw)
{
  const float* s; bf16* d; int n;
  switch (blockIdx.y) {
    case 0:  s = s0; d = d0; n = n0; break;
    case 1:  s = s1; d = d1; n = nw; break;
    case 2:  s = s2; d = d2; n = nw; break;
    case 3:  s = s3; d = d3; n = nw; break;
    default: s = s4; d = d4; n = nw; break;
  }
  const int i = (blockIdx.x * 256 + threadIdx.x) * 8;
  if (i >= n) return;
  float4 v0 = *(const float4*)(s + i);
  float4 v1 = *(const float4*)(s + i + 4);
  bf16x8 o;
  o[0] = (bf16)v0.x; o[1] = (bf16)v0.y; o[2] = (bf16)v0.z; o[3] = (bf16)v0.w;
  o[4] = (bf16)v1.x; o[5] = (bf16)v1.y; o[6] = (bf16)v1.z; o[7] = (bf16)v1.w;
  *(bf16x8*)(d + i) = o;
}

// ---------------------------------------------------------------------------
// GEMM: Y[m,n] = sum_k X[m,k]*W[n,k] + bias[n], all-bf16, fp32 bias.
// 128x128 tile, BK=32. Double-buffered LDS + glds16, ONE barrier per iter:
// sync (drain prev async loads) -> issue glds(k+1, other buf) -> MFMA(k).
// The vmcnt drain at each barrier lands after a full MFMA phase of cover.
// ---------------------------------------------------------------------------
template <typename TY>
__global__ __launch_bounds__(256) void gemm_bt_bias(
    const bf16* __restrict__ X,
    const bf16* __restrict__ W0, const bf16* __restrict__ W1, const bf16* __restrict__ W2,
    const float* __restrict__ b0, const float* __restrict__ b1, const float* __restrict__ b2,
    TY* __restrict__ Y0, TY* __restrict__ Y1, TY* __restrict__ Y2,
    int M, int N, int K)
{
  const bf16* W; const float* bias; TY* Y;
  if (blockIdx.z == 0)      { W = W0; bias = b0; Y = Y0; }
  else if (blockIdx.z == 1) { W = W1; bias = b1; Y = Y1; }
  else                      { W = W2; bias = b2; Y = Y2; }

  __shared__ __align__(16) bf16 As[2][128 * 32];
  __shared__ __align__(16) bf16 Bs[2][128 * 32];

  const int tid  = threadIdx.x;
  const int lane = tid & 63;
  const int wave = tid >> 6;
  const int m0 = blockIdx.y * 128;
  const int n0 = blockIdx.x * 128;
  const int wm = (wave >> 1) * 64;
  const int wn = (wave & 1) * 64;

  // per-thread glds source coords (chunk id = it*256+tid over 16B chunks)
  const int r0 = tid >> 2,            c0 = (tid & 3) * 8;
  const int r1 = (256 + tid) >> 2,    c1 = ((256 + tid) & 3) * 8;
  const int cb0 = (wave * 64) * 8;            // wave-uniform LDS elem base, it=0
  const int cb1 = (256 + wave * 64) * 8;      // it=1

  f32x4 acc[4][4] = {};

  // prologue: stage k0=0 into buf 0
  glds16(X + (size_t)(m0 + r0) * K + c0, &As[0][cb0]);
  glds16(W + (size_t)(n0 + r0) * K + c0, &Bs[0][cb0]);
  glds16(X + (size_t)(m0 + r1) * K + c1, &As[0][cb1]);
  glds16(W + (size_t)(n0 + r1) * K + c1, &Bs[0][cb1]);

  int pb = 0;
  for (int k0 = 0; k0 < K; k0 += 32, pb ^= 1) {
    __syncthreads();   // drains vmcnt -> buf pb resident; prior reads of pb^1 done

    if (k0 + 32 < K) {
      const int kn = k0 + 32;
      glds16(X + (size_t)(m0 + r0) * K + kn + c0, &As[pb ^ 1][cb0]);
      glds16(W + (size_t)(n0 + r0) * K + kn + c0, &Bs[pb ^ 1][cb0]);
      glds16(X + (size_t)(m0 + r1) * K + kn + c1, &As[pb ^ 1][cb1]);
      glds16(W + (size_t)(n0 + r1) * K + kn + c1, &Bs[pb ^ 1][cb1]);
    }

    bf16x8 a[4], b[4];
#pragma unroll
    for (int i = 0; i < 4; ++i)
      a[i] = *(const bf16x8*)&As[pb][(wm + i * 16 + (lane & 15)) * 32 + (lane >> 4) * 8];
#pragma unroll
    for (int i = 0; i < 4; ++i)
      b[i] = *(const bf16x8*)&Bs[pb][(wn + i * 16 + (lane & 15)) * 32 + (lane >> 4) * 8];
#pragma unroll
    for (int mi = 0; mi < 4; ++mi)
#pragma unroll
      for (int ni = 0; ni < 4; ++ni)
        acc[mi][ni] = __builtin_amdgcn_mfma_f32_16x16x32_bf16(a[mi], b[ni], acc[mi][ni], 0, 0, 0);
  }

#pragma unroll
  for (int mi = 0; mi < 4; ++mi) {
    const int row = m0 + wm + mi * 16 + (lane >> 4) * 4;
#pragma unroll
    for (int ni = 0; ni < 4; ++ni) {
      const int col = n0 + wn + ni * 16 + (lane & 15);
      const float bv = bias[col];
#pragma unroll
      for (int r = 0; r < 4; ++r)
        Y[(size_t)(row + r) * N + col] = (TY)(acc[mi][ni][r] + bv);
    }
  }
}

// ---------------------------------------------------------------------------
// Flash attention, causal, transposed-score orientation, exp2-domain softmax.
// Block: 256 thr (4 waves), TWO 64-row q-tiles (qt, 31-qt) -> 17 iters/block.
// Wave owns 16 q-rows; lane's row = l15. Mask applied only on last k-iter.
// ---------------------------------------------------------------------------
__global__ __launch_bounds__(256) void attn_causal(
    const bf16* __restrict__ Q, const bf16* __restrict__ K,
    const bf16* __restrict__ V, bf16* __restrict__ O)
{
  const int pair = blockIdx.x;         // 0..15
  const int bh   = blockIdx.y;         // 0..31
  const int b    = bh >> 4;
  const int h    = bh & 15;

  const int tid  = threadIdx.x;
  const int lane = tid & 63;
  const int wave = tid >> 6;
  const int quad = lane >> 4;
  const int l15  = lane & 15;
  const size_t headoff = (size_t)b * S_ * H_ + (size_t)h * HD_;
  const float SCL = 0.125f * 1.44269504f;   // (1/sqrt(64)) * log2(e)

  __shared__ __align__(16) bf16 Qs[64 * ST];
  __shared__ __align__(16) bf16 Ks[128 * ST];
  __shared__ __align__(16) bf16 Vt[64 * STV];       // Vt[d][key]
  __shared__ __align__(16) bf16 Ps[4][16 * STV];    // P[qrow][key] per wave

  for (int phase = 0; phase < 2; ++phase) {
    const int qt = phase ? (31 - pair) : pair;
    const int q0 = qt * 64;
    __syncthreads();   // prior phase done reading Qs

#pragma unroll
    for (int it = 0; it < 2; ++it) {
      const int c = it * 256 + tid, row = c >> 3, col = (c & 7) * 8;
      *(bf16x8*)&Qs[row * ST + col] =
          *(const bf16x8*)(Q + headoff + (size_t)(q0 + row) * H_ + col);
    }

    const int qrow = q0 + wave * 16 + l15;
    float mr = -1e30f, lr = 0.0f;
    f32x4 oacc[4] = {};

    const int niter = (qt >> 1) + 1;
    for (int it = 0; it < niter; ++it) {
      const int k0 = it * 128;
      __syncthreads();

      // stage K tile 128x64
#pragma unroll
      for (int j = 0; j < 4; ++j) {
        const int c = j * 256 + tid, row = c >> 3, col = (c & 7) * 8;
        *(bf16x8*)&Ks[row * ST + col] =
            *(const bf16x8*)(K + headoff + (size_t)(k0 + row) * H_ + col);
      }
      // stage V transposed
      {
        const int vr = (tid & 63) * 2;
        const int vc = (tid >> 6) * 16;
        bf16x8 a0 = *(const bf16x8*)(V + headoff + (size_t)(k0 + vr) * H_ + vc);
        bf16x8 a1 = *(const bf16x8*)(V + headoff + (size_t)(k0 + vr) * H_ + vc + 8);
        bf16x8 c0 = *(const bf16x8*)(V + headoff + (size_t)(k0 + vr + 1) * H_ + vc);
        bf16x8 c1 = *(const bf16x8*)(V + headoff + (size_t)(k0 + vr + 1) * H_ + vc + 8);
#pragma unroll
        for (int e = 0; e < 8; ++e) {
          bf16x2 p0; p0[0] = a0[e]; p0[1] = c0[e];
          *(bf16x2*)&Vt[(vc + e) * STV + vr] = p0;
          bf16x2 p1; p1[0] = a1[e]; p1[1] = c1[e];
          *(bf16x2*)&Vt[(vc + 8 + e) * STV + vr] = p1;
        }
      }
      __syncthreads();

      // ---- S^T = K Q^T ----
      f32x4 sacc[8] = {};
#pragma unroll
      for (int ks = 0; ks < 2; ++ks) {
        bf16x8 bq = *(const bf16x8*)&Qs[(wave * 16 + l15) * ST + ks * 32 + quad * 8];
#pragma unroll
        for (int mb = 0; mb < 8; ++mb) {
          bf16x8 ak = *(const bf16x8*)&Ks[(mb * 16 + l15) * ST + ks * 32 + quad * 8];
          sacc[mb] = __builtin_amdgcn_mfma_f32_16x16x32_bf16(ak, bq, sacc[mb], 0, 0, 0);
        }
      }

      // scale (log2 domain); mask only on the final k-tile
      float sv[8][4];
      if (it == niter - 1) {
#pragma unroll
        for (int mb = 0; mb < 8; ++mb) {
          const int kb = k0 + mb * 16 + quad * 4;
#pragma unroll
          for (int r = 0; r < 4; ++r) {
            const float s = sacc[mb][r] * SCL;
            sv[mb][r] = (kb + r > qrow) ? -1e30f : s;
          }
        }
      } else {
#pragma unroll
        for (int mb = 0; mb < 8; ++mb)
#pragma unroll
          for (int r = 0; r < 4; ++r)
            sv[mb][r] = sacc[mb][r] * SCL;
      }

      // row max: in-lane tree + 2 shuffles
      float mx = -1e30f;
#pragma unroll
      for (int mb = 0; mb < 8; ++mb)
        mx = fmaxf(mx, fmaxf(fmaxf(sv[mb][0], sv[mb][1]), fmaxf(sv[mb][2], sv[mb][3])));
      mx = fmaxf(mx, __shfl_xor(mx, 16, 64));
      mx = fmaxf(mx, __shfl_xor(mx, 32, 64));
      const float mnew  = fmaxf(mr, mx);
      const float alpha = __builtin_amdgcn_exp2f(mr - mnew);
      mr = mnew;

      // exp2, P write (b64 contiguous), sum
      float sum = 0.0f;
#pragma unroll
      for (int mb = 0; mb < 8; ++mb) {
        bf16x4 pw;
#pragma unroll
        for (int r = 0; r < 4; ++r) {
          const float p = __builtin_amdgcn_exp2f(sv[mb][r] - mnew);
          sum += p;
          pw[r] = (bf16)p;
        }
        *(bf16x4*)&Ps[wave][l15 * STV + mb * 16 + quad * 4] = pw;
      }
      sum += __shfl_xor(sum, 16, 64);
      sum += __shfl_xor(sum, 32, 64);
      lr = lr * alpha + sum;
#pragma unroll
      for (int mb = 0; mb < 4; ++mb)
#pragma unroll
        for (int r = 0; r < 4; ++r) oacc[mb][r] *= alpha;

      // ---- O^T += V^T P^T ----
#pragma unroll
      for (int ks = 0; ks < 4; ++ks) {
        bf16x8 bp = *(const bf16x8*)&Ps[wave][l15 * STV + ks * 32 + quad * 8];
#pragma unroll
        for (int mb = 0; mb < 4; ++mb) {
          bf16x8 av = *(const bf16x8*)&Vt[(mb * 16 + l15) * STV + ks * 32 + quad * 8];
          oacc[mb] = __builtin_amdgcn_mfma_f32_16x16x32_bf16(av, bp, oacc[mb], 0, 0, 0);
        }
      }
    }

    // epilogue
    const float inv = 1.0f / lr;
#pragma unroll
    for (int mb = 0; mb < 4; ++mb) {
      bf16x4 o;
#pragma unroll
      for (int r = 0; r < 4; ++r) o[r] = (bf16)(oacc[mb][r] * inv);
      *(bf16x4*)(O + headoff + (size_t)qrow * H_ + mb * 16 + quad * 4) = o;
    }
  }
}

extern "C" void kernel_launch(void* const* d_in, const int* in_sizes, int n_in,
                              void* d_out, int out_size, void* d_ws, size_t ws_size,
                              hipStream_t stream) {
  const float* hs = (const float*)d_in[0];
  const float* Wq = (const float*)d_in[1]; const float* bq = (const float*)d_in[2];
  const float* Wk = (const float*)d_in[3]; const float* bk = (const float*)d_in[4];
  const float* Wv = (const float*)d_in[5]; const float* bv = (const float*)d_in[6];
  const float* Wo = (const float*)d_in[7]; const float* bo = (const float*)d_in[8];
  float* out = (float*)d_out;

  const size_t elems = (size_t)B_ * S_ * H_;   // 4,194,304
  const size_t wel   = (size_t)H_ * H_;        // 1,048,576
  // workspace (40 MB): [hsb | AO aliased 8MB][W bf16 8MB][Q 8][K 8][V 8]
  bf16* hsb = (bf16*)d_ws;      // read only by QKV GEMM
  bf16* AO  = hsb;              // written by attn (hsb dead by then)
  bf16* Wqb = hsb + elems;
  bf16* Wkb = Wqb + wel;
  bf16* Wvb = Wkb + wel;
  bf16* Wob = Wvb + wel;
  bf16* Qw  = Wob + wel;
  bf16* Kw  = Qw + elems;
  bf16* Vw  = Kw + elems;

  cvt_f32_bf16<<<dim3(2048, 5), dim3(256), 0, stream>>>(
      hs, hsb, (int)elems, Wq, Wqb, Wk, Wkb, Wv, Wvb, Wo, Wob, (int)wel);

  const int M = B_ * S_;   // 4096
  gemm_bt_bias<bf16><<<dim3(H_ / 128, M / 128, 3), dim3(256), 0, stream>>>(
      hsb, Wqb, Wkb, Wvb, bq, bk, bv, Qw, Kw, Vw, M, H_, H_);

  attn_causal<<<dim3(16, B_ * NH_), dim3(256), 0, stream>>>(Qw, Kw, Vw, AO);

  gemm_bt_bias<float><<<dim3(H_ / 128, M / 128, 1), dim3(256), 0, stream>>>(
      AO, Wob, Wob, Wob, bo, bo, bo, out, out, out, M, H_, H_);
}